// Round 10
// baseline (310.455 us; speedup 1.0000x reference)
//
#include <hip/hip_runtime.h>

// DirectInterpGNN — segment-sum over 16M edges into 500K vertices, coef, gather.
// Round 10: r9 falsified DS-bound (halved DS ops, same 157us). Remaining model:
// mixed-BW / partial-line-write ceiling (~2.7TB/s cold, WRITE amp 264 vs 160MB).
// Fix: (1) pad16-aligned per-(block,bin) segments -> full-line flushes, zero-pad
// records (harmless in fixed-point accum); (2) delete hist+scans: fixed per-bin
// capacity C regions + one global atomicAdd(gcur[b], pad16(cnt)) per block-bin.
// Order within bins is allocation-order (non-deterministic) but u64 fixed-point
// accumulation is order-independent -> deterministic output.
//
// ws: coef[nv] | gcur[BINS] | partial[BINS*SPLIT*VPB]u64 | rec[BINS*C]*8B | ah[ne]*2B

#define BINS 256
#define VSHIFT 11
#define VPB 2048          // vertices per bin = 1<<VSHIFT
#define NBLK 1024         // scatter blocks
#define BT 256            // threads (accum_part, coef, finalize)
#define SBT 512           // threads (scatter)
#define SUB 2048          // edges per sub-chunk (LDS-staged)
#define SPLIT 8           // record slices per bin in accum
#define CAP 16            // staged slots per bin per sub-chunk
#define C_PER_BIN 76800u  // per-bin record capacity (padded mean 73728 + >10 sigma)

#define SC_A 524288.0f    // 2^19 (a in [0.1,1.1] -> ni <= 577K)
#define SC_D 4194304.0f   // 2^22 (d in [0.001,1.34] -> di <= 5.6M)

typedef unsigned int u32;
typedef unsigned short u16;
typedef unsigned long long u64;

static __device__ __forceinline__ u32 f2h(float x) {
    _Float16 h = (_Float16)x; u16 u; __builtin_memcpy(&u, &h, 2); return (u32)u;
}
static __device__ __forceinline__ float h2f(u32 u) {
    u16 v = (u16)u; _Float16 h; __builtin_memcpy(&h, &v, 2); return (float)h;
}

// ---------------- main path ----------------

__global__ void zero_gcur_k(u32* __restrict__ gcur) {
    if (threadIdx.x < BINS) gcur[threadIdx.x] = 0u;
}

__global__ __launch_bounds__(SBT, 2)
void scatter_k(const float* __restrict__ eattr,
               const int* __restrict__ src,
               u32* __restrict__ gcur,
               uint2* __restrict__ rec,
               u16* __restrict__ ah,
               int ne, int chunk) {
    __shared__ u32 cur[BINS];            // running cursor (relative, this block)
    __shared__ u32 cnt[BINS];            // per-sub-chunk allocation counter
    __shared__ u32 cnt_all[BINS];        // whole-chunk per-bin count (pass A)
    __shared__ u32 sstart[BINS];         // this block's segment start per bin
    __shared__ uint2 stage[BINS * CAP];  // 32 KB
    int t = threadIdx.x;
    int lo = blockIdx.x * chunk;         // chunk is a multiple of SUB
    int hi = min(ne, lo + chunk);
    if (lo >= hi) return;

    // ---- pass A: count this chunk per bin ----
    if (t < BINS) cnt_all[t] = 0u;
    __syncthreads();
    {
        int n = hi - lo;
        int ng = (n + 3) >> 2;
        for (int g = t; g < ng; g += SBT) {
            int i = lo + (g << 2);
            if (i + 3 < hi) {
                int4 s = *reinterpret_cast<const int4*>(src + i);
                atomicAdd(&cnt_all[((u32)s.x) >> VSHIFT], 1u);
                atomicAdd(&cnt_all[((u32)s.y) >> VSHIFT], 1u);
                atomicAdd(&cnt_all[((u32)s.z) >> VSHIFT], 1u);
                atomicAdd(&cnt_all[((u32)s.w) >> VSHIFT], 1u);
            } else {
                for (int j = i; j < hi; ++j)
                    atomicAdd(&cnt_all[((u32)src[j]) >> VSHIFT], 1u);
            }
        }
    }
    __syncthreads();
    // ---- allocate aligned segment per bin (one global atomic per block-bin) ----
    if (t < BINS) {
        u32 p = (cnt_all[t] + 15u) & ~15u;   // 128B-aligned capacity
        u32 s0 = p ? atomicAdd(&gcur[t], p) : 0u;
        sstart[t] = s0;
        cur[t] = s0;
    }
    // (first loop barrier publishes cur/sstart)

    // register double buffer: er = [A0 S0 v0 A1 S1 v1 A2 S2 v2 A3 S3 v3]
    float erA[12], erB[12];
    int srA[4], srB[4];

    auto LOADV = [&](int base, float* er, int* sr) {
        int o = t << 2;
        int n = min(hi - base, SUB);
        int i = base + o;
        if (o + 3 < n) {
            int4 s4 = *reinterpret_cast<const int4*>(src + i);
            sr[0] = s4.x; sr[1] = s4.y; sr[2] = s4.z; sr[3] = s4.w;
            const float4* ea = reinterpret_cast<const float4*>(eattr + 3ll * i);
            float4 w0 = ea[0], w1 = ea[1], w2 = ea[2];
            er[0] = w0.x; er[1] = w0.y; er[2]  = w0.z; er[3]  = w0.w;
            er[4] = w1.x; er[5] = w1.y; er[6]  = w1.z; er[7]  = w1.w;
            er[8] = w2.x; er[9] = w2.y; er[10] = w2.z; er[11] = w2.w;
        } else {
            #pragma unroll
            for (int j = 0; j < 4; ++j) {
                if (o + j < n) {
                    sr[j] = src[i + j];
                    er[3 * j]     = eattr[3ll * (i + j)];
                    er[3 * j + 1] = eattr[3ll * (i + j) + 1];
                    er[3 * j + 2] = eattr[3ll * (i + j) + 2];
                }
            }
        }
    };

    auto PLACE = [&](int base, float* er, int* sr) {
        int o = t << 2;
        int n = min(hi - base, SUB);
        ushort4 hv;
        u16* hp = &hv.x;
        #pragma unroll
        for (int j = 0; j < 4; ++j) {
            if (o + j < n) {
                u32 s = (u32)sr[j];
                float a = er[3 * j];
                float d = a * er[3 * j + 1] * er[3 * j + 2];
                u32 ni = __float2uint_rn(a * SC_A);
                u32 di = __float2uint_rn(d * SC_D);
                u32 b = s >> VSHIFT;
                uint2 pay = make_uint2(di, (ni << VSHIFT) | (s & (VPB - 1)));
                hp[j] = (u16)f2h(a);
                u32 slot = atomicAdd(&cnt[b], 1u);
                if (slot < CAP) stage[(b << 4) | slot] = pay;
                else rec[(size_t)b * C_PER_BIN + cur[b] + slot] = pay;  // rare
            }
        }
        if (o + 3 < n) {
            *reinterpret_cast<ushort4*>(ah + base + o) = hv;
        } else {
            #pragma unroll
            for (int j = 0; j < 4; ++j)
                if (o + j < n) ah[base + o + j] = hp[j];
        }
    };

    LOADV(lo, erA, srA);
    for (int base = lo; base < hi; base += SUB) {
        if (t < BINS) cnt[t] = 0u;
        __syncthreads();
        PLACE(base, erA, srA);
        if (base + SUB < hi) LOADV(base + SUB, erB, srB);   // prefetch
        __syncthreads();
        // flush staged slots: consecutive within each block-bin segment
        #pragma unroll
        for (int r = 0; r < (BINS * CAP) / SBT; ++r) {      // 8
            int j = t + r * SBT;
            u32 b = (u32)j >> 4, s = (u32)j & 15u;
            u32 c = cnt[b];
            if (s < min(c, (u32)CAP))
                rec[(size_t)b * C_PER_BIN + cur[b] + s] = stage[j];
        }
        __syncthreads();
        if (t < BINS) cur[t] += cnt[t];
        #pragma unroll
        for (int j = 0; j < 12; ++j) erA[j] = erB[j];
        #pragma unroll
        for (int j = 0; j < 4; ++j) srA[j] = srB[j];
    }
    // ---- zero-fill alignment pads (zero-records: harmless in accum) ----
    if (t < BINS) {
        u32 end = sstart[t] + ((cnt_all[t] + 15u) & ~15u);
        for (u32 i = cur[t]; i < end; ++i)
            rec[(size_t)t * C_PER_BIN + i] = make_uint2(0u, 0u);
    }
}

// one block per (bin, slice); single u64 LDS atomic per record
__global__ void accum_part_k(const uint2* __restrict__ rec,
                             const u32* __restrict__ gcur,
                             u64* __restrict__ partial) {
    __shared__ u64 acc[VPB];   // 16 KB
    int bin = blockIdx.x / SPLIT;
    int q   = blockIdx.x % SPLIT;
    for (int l = threadIdx.x; l < VPB; l += BT) acc[l] = 0ull;
    __syncthreads();
    u32 T = gcur[bin];                 // padded record count in this bin
    const uint2* rb_ = rec + (size_t)bin * C_PER_BIN;
    u32 ra  = (u32)((u64)T * q / SPLIT);
    u32 rbn = (u32)((u64)T * (q + 1) / SPLIT);
    for (u32 r = ra + threadIdx.x; r < rbn; r += BT) {
        uint2 qq = rb_[r];
        // num field: ni @2^19 -> <<3 for 2^22 scale, at bit 32 => <<35
        u64 add = ((u64)(qq.y >> VSHIFT) << 35) | (u64)qq.x;
        atomicAdd(&acc[qq.y & (VPB - 1)], add);
    }
    __syncthreads();
    u64* po = partial + (size_t)blockIdx.x * VPB;
    for (int l = threadIdx.x; l < VPB; l += BT) po[l] = acc[l];
}

__global__ void coef_part_k(const u64* __restrict__ partial,
                            const float* __restrict__ vattr,
                            float* __restrict__ coef, int nv) {
    int v = blockIdx.x * blockDim.x + threadIdx.x;
    int stride = gridDim.x * blockDim.x;
    for (; v < nv; v += stride) {
        int bin = v >> VSHIFT, l = v & (VPB - 1);
        size_t base = ((size_t)bin * SPLIT << VSHIFT) + l;
        float num = 0.f, den = 0.f;
        #pragma unroll
        for (int sp = 0; sp < SPLIT; ++sp) {
            u64 p = partial[base + ((size_t)sp << VSHIFT)];
            num += (float)(u32)(p >> 32);
            den += (float)(u32)p;
        }
        // both fields at scale 2^22; gammabar = num/den is scale-free
        float2 va = reinterpret_cast<const float2*>(vattr)[v];  // (A_ii, C_i)
        float gam = num / den;   // NaN only for edgeless vertices; never gathered
        coef[v] = (1.0f - va.y) * (-gam / va.x);
    }
}

// ---------------- fallback path (ws too small): packed u64 atomics ----------------

#define FPSCALE 8388608.0f      // 2^23
#define FPINV   (1.0f / 8388608.0f)

__global__ void zero_u64(u64* __restrict__ p, int n) {
    int i = blockIdx.x * blockDim.x + threadIdx.x;
    int stride = gridDim.x * blockDim.x;
    for (; i < n; i += stride) p[i] = 0ull;
}

__global__ void accum_packed(const float* __restrict__ eattr,
                             const int* __restrict__ src,
                             u64* __restrict__ accp,
                             u16* __restrict__ ah, int ne) {
    int t = blockIdx.x * blockDim.x + threadIdx.x;
    int stride = gridDim.x * blockDim.x;
    for (int i = t; i < ne; i += stride) {
        float a = eattr[3ll * i];
        float d = a * eattr[3ll * i + 1] * eattr[3ll * i + 2];
        u32 ni = (u32)__float2uint_rn(a * FPSCALE);
        u32 di = (u32)__float2uint_rn(d * FPSCALE);
        atomicAdd(&accp[(u32)src[i]], ((u64)ni << 32) | (u64)di);
        if (ah) ah[i] = (u16)f2h(a);
    }
}

__global__ void coef_packed(const float* __restrict__ vattr,
                            const u64* __restrict__ accp,
                            float* __restrict__ coef, int nv) {
    int v = blockIdx.x * blockDim.x + threadIdx.x;
    int stride = gridDim.x * blockDim.x;
    for (; v < nv; v += stride) {
        u64 a = accp[v];
        float num = (float)(u32)(a >> 32) * FPINV;
        float den = (float)(u32)a * FPINV;
        float2 va = reinterpret_cast<const float2*>(vattr)[v];
        coef[v] = (1.0f - va.y) * (-(num / den) / va.x);
    }
}

// ---------------- finalize (shared) ----------------

__global__ void finalize(const u16* __restrict__ ah,
                         const float* __restrict__ edge_attr,
                         const int* __restrict__ src,
                         const float* __restrict__ coef,
                         float* __restrict__ out, int ne4, int n_edges) {
    int t = blockIdx.x * blockDim.x + threadIdx.x;
    int stride = gridDim.x * blockDim.x;
    for (int i = t; i < ne4; i += stride) {
        int4 s = reinterpret_cast<const int4*>(src)[i];
        float4 A;
        if (ah) {
            ushort4 h = reinterpret_cast<const ushort4*>(ah)[i];
            A.x = h2f(h.x); A.y = h2f(h.y); A.z = h2f(h.z); A.w = h2f(h.w);
        } else {
            const float* e = edge_attr + 12ll * i;
            A.x = e[0]; A.y = e[3]; A.z = e[6]; A.w = e[9];
        }
        float4 w;
        w.x = coef[s.x] * A.x;
        w.y = coef[s.y] * A.y;
        w.z = coef[s.z] * A.z;
        w.w = coef[s.w] * A.w;
        reinterpret_cast<float4*>(out)[i] = w;
    }
    for (int e = 4 * ne4 + t; e < n_edges; e += stride) {
        float Ae = ah ? h2f(ah[e]) : edge_attr[3ll * e];
        out[e] = coef[src[e]] * Ae;
    }
}

extern "C" void kernel_launch(void* const* d_in, const int* in_sizes, int n_in,
                              void* d_out, int out_size, void* d_ws, size_t ws_size,
                              hipStream_t stream) {
    const float* vattr = (const float*)d_in[0];   // (nv, 2)
    const float* eattr = (const float*)d_in[1];   // (ne, 3)
    const int*   pair  = (const int*)d_in[2];     // (2, ne)
    int nv = in_sizes[0] / 2;
    int ne = in_sizes[1] / 3;
    const int* src = pair;                         // row 0
    float* out = (float*)d_out;

    int ne4 = ne / 4;
    auto capped = [](long long want, int cap) {
        return (int)(want < cap ? (want > 1 ? want : 1) : cap);
    };
    int fgrid = capped(((long long)ne4 + BT - 1) / BT, 4096);

    // main-path ws layout
    size_t off = 0;
    float* coef = (float*)((char*)d_ws + off); off += (size_t)nv * 4;
    off = (off + 255) & ~(size_t)255;
    u32* gcur = (u32*)((char*)d_ws + off); off += (size_t)BINS * 4;
    off = (off + 255) & ~(size_t)255;
    u64* partial = (u64*)((char*)d_ws + off); off += ((size_t)BINS * SPLIT << VSHIFT) * 8;
    off = (off + 255) & ~(size_t)255;
    uint2* rec = (uint2*)((char*)d_ws + off); off += (size_t)BINS * C_PER_BIN * 8;
    off = (off + 255) & ~(size_t)255;
    u16* ah = (u16*)((char*)d_ws + off); off += 2ull * ne;
    // chunk: multiple of SUB so sub-chunk bases stay 4-aligned for int4/float4
    long long chunk_ll = ((((long long)ne + NBLK - 1) / NBLK) + SUB - 1) / SUB * SUB;
    // capacity check: padded per-bin total must fit C_PER_BIN with margin
    bool main_ok = ws_size >= off && nv <= (BINS << VSHIFT) &&
                   chunk_ll * NBLK < 2147000000ll &&
                   (u32)(ne / BINS + NBLK * 8 + 4096) <= C_PER_BIN;
    int chunk = (int)chunk_ll;

    if (main_ok) {
        zero_gcur_k<<<1, BINS, 0, stream>>>(gcur);
        scatter_k<<<NBLK, SBT, 0, stream>>>(eattr, src, gcur, rec, ah, ne, chunk);
        accum_part_k<<<BINS * SPLIT, BT, 0, stream>>>(rec, gcur, partial);
        coef_part_k<<<capped(((long long)nv + BT - 1) / BT, 2048), BT, 0, stream>>>(partial, vattr, coef, nv);
        finalize<<<fgrid, BT, 0, stream>>>(ah, eattr, src, coef, out, ne4, ne);
    } else {
        // fallback: packed u64 atomics
        u64* accp = (u64*)d_ws;
        float* fcoef = (float*)(accp + nv);
        size_t fb_base = (size_t)nv * 12;
        fb_base = (fb_base + 255) & ~(size_t)255;
        u16* fah = nullptr;
        if (ws_size >= fb_base + 2ull * ne)
            fah = (u16*)((char*)d_ws + fb_base);
        int zgrid = capped(((long long)nv + BT - 1) / BT, 2048);
        int agrid = capped(((long long)ne + BT - 1) / BT, 4096);
        int cgrid = capped(((long long)nv + BT - 1) / BT, 2048);
        zero_u64<<<zgrid, BT, 0, stream>>>(accp, nv);
        accum_packed<<<agrid, BT, 0, stream>>>(eattr, src, accp, fah, ne);
        coef_packed<<<cgrid, BT, 0, stream>>>(vattr, accp, fcoef, nv);
        finalize<<<fgrid, BT, 0, stream>>>(fah, eattr, src, fcoef, out, ne4, ne);
    }
}

// Round 11
// 243.346 us; speedup vs baseline: 1.2758x; 1.2758x over previous
//
#include <hip/hip_runtime.h>

// DirectInterpGNN — segment-sum over 16M edges into 500K vertices, coef, gather.
// Round 11: r10 regressed (fused count pass + false alignment fix) -> revert to
// r8 counting-sort scatter. New model: flush-run length drives write amp
// (SUB=2048 -> 8-rec/64B runs -> 1.65x amp). Fix: SUB=4096 at BINS=256 with
// u8 sbin -> 16-rec/128B runs, LDS ~39KB keeps 4 blk/CU x 8 waves. Halves
// barriers/edge. hist+scans separate (r10 lesson); finalize 512 threads.
//
// ws: coef[nv] | bin_total | bin_base | bh[NBLK*BINS] | partial[BINS*SPLIT*VPB]u64
//     | rec[ne]*8B | ah[ne]*2B

#define BINS 256
#define VSHIFT 11
#define VPB 2048         // vertices per bin = 1<<VSHIFT
#define NBLK 1024        // partition blocks
#define BT 256           // threads (scans, accum_part, coef)
#define SBT 512          // threads (hist, scatter)
#define FBT 512          // threads (finalize)
#define SUB 4096         // edges per sub-chunk (LDS-staged)
#define SPLIT 8          // record slices per bin in accum

#define SC_A 524288.0f    // 2^19 (a in [0.1,1.1] -> ni <= 577K)
#define SC_D 4194304.0f   // 2^22 (d in [0.001,1.34] -> di <= 5.6M)

typedef unsigned int u32;
typedef unsigned short u16;
typedef unsigned char u8;
typedef unsigned long long u64;

static __device__ __forceinline__ u32 f2h(float x) {
    _Float16 h = (_Float16)x; u16 u; __builtin_memcpy(&u, &h, 2); return (u32)u;
}
static __device__ __forceinline__ float h2f(u32 u) {
    u16 v = (u16)u; _Float16 h; __builtin_memcpy(&h, &v, 2); return (float)h;
}

// ---------------- main path ----------------

__global__ void hist_k(const int* __restrict__ src, int ne, int chunk,
                       u32* __restrict__ bh) {
    __shared__ u32 h[BINS];
    if (threadIdx.x < BINS) h[threadIdx.x] = 0;
    __syncthreads();
    int lo = blockIdx.x * chunk;            // chunk multiple of SUB -> 4-aligned
    int hi = min(ne, lo + chunk);
    int n = hi - lo;
    int ngroups = (n + 3) >> 2;
    for (int g = threadIdx.x; g < ngroups; g += SBT) {
        int i = lo + (g << 2);
        if (i + 3 < hi) {
            int4 s = *reinterpret_cast<const int4*>(src + i);
            atomicAdd(&h[((u32)s.x) >> VSHIFT], 1u);
            atomicAdd(&h[((u32)s.y) >> VSHIFT], 1u);
            atomicAdd(&h[((u32)s.z) >> VSHIFT], 1u);
            atomicAdd(&h[((u32)s.w) >> VSHIFT], 1u);
        } else {
            for (int j = i; j < hi; ++j)
                atomicAdd(&h[((u32)src[j]) >> VSHIFT], 1u);
        }
    }
    __syncthreads();
    if (threadIdx.x < BINS)
        bh[(size_t)blockIdx.x * BINS + threadIdx.x] = h[threadIdx.x];
}

// per-bin column scan over NBLK block counts -> exclusive offsets (in place)
// + bin_total. grid = BINS, block = BT
__global__ void scan_col_k(u32* __restrict__ bh, u32* __restrict__ bin_total) {
    const int IT = NBLK / BT;   // 4
    int bin = blockIdx.x, t = threadIdx.x;
    u32 v[IT];
    u32 tsum = 0;
    #pragma unroll
    for (int k = 0; k < IT; ++k) {
        v[k] = bh[(size_t)(IT * t + k) * BINS + bin];
        tsum += v[k];
    }
    int lane = t & 63, wv = t >> 6;
    u32 inc = tsum;
    #pragma unroll
    for (int d = 1; d < 64; d <<= 1) {
        u32 y = __shfl_up(inc, d);
        if (lane >= d) inc += y;
    }
    __shared__ u32 wsum[BT / 64];
    if (lane == 63) wsum[wv] = inc;
    __syncthreads();
    u32 wbase = 0;
    for (int w = 0; w < wv; ++w) wbase += wsum[w];
    u32 run = wbase + inc - tsum;   // exclusive base for this thread
    #pragma unroll
    for (int k = 0; k < IT; ++k) {
        u32 c = v[k];
        bh[(size_t)(IT * t + k) * BINS + bin] = run;
        run += c;
    }
    if (t == BT - 1) bin_total[bin] = run;
}

// exclusive scan over BINS totals -> bin_base[0..BINS]. single block, BT>=BINS.
__global__ void scan_bins_k(const u32* __restrict__ bin_total,
                            u32* __restrict__ bin_base) {
    int t = threadIdx.x;
    u32 a0 = (t < BINS) ? bin_total[t] : 0;
    int lane = t & 63, wv = t >> 6;
    u32 inc = a0;
    #pragma unroll
    for (int d = 1; d < 64; d <<= 1) {
        u32 y = __shfl_up(inc, d);
        if (lane >= d) inc += y;
    }
    __shared__ u32 wsum[BT / 64];
    if (lane == 63) wsum[wv] = inc;
    __syncthreads();
    u32 wbase = 0;
    for (int w = 0; w < wv; ++w) wbase += wsum[w];
    if (t < BINS) bin_base[t] = wbase + inc - a0;
    if (t == BINS - 1) bin_base[BINS] = wbase + inc;  // == ne
}

__global__ __launch_bounds__(SBT, 2)
void scatter_k(const float* __restrict__ eattr,
               const int* __restrict__ src,
               const u32* __restrict__ bh,
               const u32* __restrict__ bin_base,
               uint2* __restrict__ rec,
               u16* __restrict__ ah,
               int ne, int chunk) {
    __shared__ u32 cur[BINS];     // running global cursor per bin (this block)
    __shared__ u32 lbase[BINS];   // sub-chunk hist, then exclusive scan
    __shared__ u32 loff[BINS];    // alloc cursor within sub-chunk
    __shared__ u32 wsum[SBT / 64];
    __shared__ uint2 stage[SUB];  // 32 KB
    __shared__ u8 sbin[SUB];      // 4 KB
    int t = threadIdx.x;
    int lane = t & 63, wid = t >> 6;
    if (t < BINS)
        cur[t] = bin_base[t] + bh[(size_t)blockIdx.x * BINS + t];
    int lo = blockIdx.x * chunk;          // chunk is a multiple of SUB
    int hi = min(ne, lo + chunk);
    for (int base = lo; base < hi; base += SUB) {
        int n = min(SUB, hi - base);
        if (t < BINS) lbase[t] = 0;
        __syncthreads();
        // 8 edges per thread in two coalesced groups of 4
        uint2 pay[8];
        u8 pb[8];
        #pragma unroll
        for (int half = 0; half < 2; ++half) {
            int g = t + half * SBT;
            int o = g << 2;                 // 0..4092
            int i = base + o;
            if (o + 3 < n) {
                int4 sv = *reinterpret_cast<const int4*>(src + i);
                const float4* ea = reinterpret_cast<const float4*>(eattr + 3ll * i);
                float4 w0 = ea[0], w1 = ea[1], w2 = ea[2];
                // (A0 S0 v0 A1)(S1 v1 A2 S2)(v2 A3 S3 v3)
                float A[4] = {w0.x, w0.w, w1.z, w2.y};
                float D[4] = {w0.x * w0.y * w0.z, w0.w * w1.x * w1.y,
                              w1.z * w1.w * w2.x, w2.y * w2.z * w2.w};
                int S[4] = {sv.x, sv.y, sv.z, sv.w};
                ushort4 hv;
                u16* hp = &hv.x;
                #pragma unroll
                for (int j = 0; j < 4; ++j) {
                    u32 s = (u32)S[j];
                    u32 ni = __float2uint_rn(A[j] * SC_A);
                    u32 di = __float2uint_rn(D[j] * SC_D);
                    u8 b = (u8)(s >> VSHIFT);
                    pay[half * 4 + j] = make_uint2(di, (ni << VSHIFT) | (s & (VPB - 1)));
                    pb[half * 4 + j] = b;
                    hp[j] = (u16)f2h(A[j]);
                    atomicAdd(&lbase[b], 1u);
                }
                *reinterpret_cast<ushort4*>(ah + i) = hv;
            } else {
                #pragma unroll
                for (int j = 0; j < 4; ++j) {
                    int o2 = o + j;
                    if (o2 < n) {
                        int i2 = base + o2;
                        u32 s = (u32)src[i2];
                        float a  = eattr[3ll * i2];
                        float s1 = eattr[3ll * i2 + 1];
                        float v1 = eattr[3ll * i2 + 2];
                        u32 ni = __float2uint_rn(a * SC_A);
                        u32 di = __float2uint_rn(a * s1 * v1 * SC_D);
                        u8 b = (u8)(s >> VSHIFT);
                        pay[half * 4 + j] = make_uint2(di, (ni << VSHIFT) | (s & (VPB - 1)));
                        pb[half * 4 + j] = b;
                        ah[i2] = (u16)f2h(a);
                        atomicAdd(&lbase[b], 1u);
                    }
                }
            }
        }
        __syncthreads();
        // exclusive scan of lbase[0..BINS), 1 item/thread (t<BINS)
        u32 a0 = (t < BINS) ? lbase[t] : 0;
        u32 inc = a0;
        #pragma unroll
        for (int d = 1; d < 64; d <<= 1) {
            u32 y = __shfl_up(inc, d);
            if (lane >= d) inc += y;
        }
        if (lane == 63) wsum[wid] = inc;
        __syncthreads();
        u32 wb = 0;
        for (int w = 0; w < wid; ++w) wb += wsum[w];
        u32 ex = wb + inc - a0;
        if (t < BINS) { lbase[t] = ex; loff[t] = ex; }
        __syncthreads();
        // place into stage (bin-sorted)
        #pragma unroll
        for (int k = 0; k < 8; ++k) {
            int o = ((t + (k >> 2) * SBT) << 2) + (k & 3);
            if (o < n) {
                u8 b = pb[k];
                u32 p = atomicAdd(&loff[b], 1u);
                stage[p] = pay[k];
                sbin[p] = b;
            }
        }
        __syncthreads();
        // coalesced flush: runs of ~16 records (128B) per bin
        for (int p = t; p < n; p += SBT) {
            u32 b = sbin[p];
            rec[cur[b] + (u32)p - lbase[b]] = stage[p];
        }
        __syncthreads();
        if (t < BINS) cur[t] += loff[t] - lbase[t];
        __syncthreads();
    }
}

// one block per (bin, slice); single u64 LDS atomic per record
__global__ void accum_part_k(const uint2* __restrict__ rec,
                             const u32* __restrict__ bin_base,
                             u64* __restrict__ partial) {
    __shared__ u64 acc[VPB];   // 16 KB
    int bin = blockIdx.x / SPLIT;
    int q   = blockIdx.x % SPLIT;
    for (int l = threadIdx.x; l < VPB; l += BT) acc[l] = 0ull;
    __syncthreads();
    u32 s0 = bin_base[bin], s1 = bin_base[bin + 1];
    u32 cnt = s1 - s0;
    u32 ra  = s0 + (u32)((u64)cnt * q / SPLIT);
    u32 rbn = s0 + (u32)((u64)cnt * (q + 1) / SPLIT);
    for (u32 r = ra + threadIdx.x; r < rbn; r += BT) {
        uint2 qq = rec[r];
        // num field: ni @2^19 -> <<3 for 2^22 scale, at bit 32 => <<35
        u64 add = ((u64)(qq.y >> VSHIFT) << 35) | (u64)qq.x;
        atomicAdd(&acc[qq.y & (VPB - 1)], add);
    }
    __syncthreads();
    u64* po = partial + (size_t)blockIdx.x * VPB;
    for (int l = threadIdx.x; l < VPB; l += BT) po[l] = acc[l];
}

__global__ void coef_part_k(const u64* __restrict__ partial,
                            const float* __restrict__ vattr,
                            float* __restrict__ coef, int nv) {
    int v = blockIdx.x * blockDim.x + threadIdx.x;
    int stride = gridDim.x * blockDim.x;
    for (; v < nv; v += stride) {
        int bin = v >> VSHIFT, l = v & (VPB - 1);
        size_t base = ((size_t)bin * SPLIT << VSHIFT) + l;
        float num = 0.f, den = 0.f;
        #pragma unroll
        for (int sp = 0; sp < SPLIT; ++sp) {
            u64 p = partial[base + ((size_t)sp << VSHIFT)];
            num += (float)(u32)(p >> 32);
            den += (float)(u32)p;
        }
        // both fields at scale 2^22; gammabar = num/den is scale-free
        float2 va = reinterpret_cast<const float2*>(vattr)[v];  // (A_ii, C_i)
        float gam = num / den;   // NaN only for edgeless vertices; never gathered
        coef[v] = (1.0f - va.y) * (-gam / va.x);
    }
}

// ---------------- fallback path (ws too small): packed u64 atomics ----------------

#define FPSCALE 8388608.0f      // 2^23
#define FPINV   (1.0f / 8388608.0f)

__global__ void zero_u64(u64* __restrict__ p, int n) {
    int i = blockIdx.x * blockDim.x + threadIdx.x;
    int stride = gridDim.x * blockDim.x;
    for (; i < n; i += stride) p[i] = 0ull;
}

__global__ void accum_packed(const float* __restrict__ eattr,
                             const int* __restrict__ src,
                             u64* __restrict__ accp,
                             u16* __restrict__ ah, int ne) {
    int t = blockIdx.x * blockDim.x + threadIdx.x;
    int stride = gridDim.x * blockDim.x;
    for (int i = t; i < ne; i += stride) {
        float a = eattr[3ll * i];
        float d = a * eattr[3ll * i + 1] * eattr[3ll * i + 2];
        u32 ni = (u32)__float2uint_rn(a * FPSCALE);
        u32 di = (u32)__float2uint_rn(d * FPSCALE);
        atomicAdd(&accp[(u32)src[i]], ((u64)ni << 32) | (u64)di);
        if (ah) ah[i] = (u16)f2h(a);
    }
}

__global__ void coef_packed(const float* __restrict__ vattr,
                            const u64* __restrict__ accp,
                            float* __restrict__ coef, int nv) {
    int v = blockIdx.x * blockDim.x + threadIdx.x;
    int stride = gridDim.x * blockDim.x;
    for (; v < nv; v += stride) {
        u64 a = accp[v];
        float num = (float)(u32)(a >> 32) * FPINV;
        float den = (float)(u32)a * FPINV;
        float2 va = reinterpret_cast<const float2*>(vattr)[v];
        coef[v] = (1.0f - va.y) * (-(num / den) / va.x);
    }
}

// ---------------- finalize (shared) ----------------

__global__ void finalize(const u16* __restrict__ ah,
                         const float* __restrict__ edge_attr,
                         const int* __restrict__ src,
                         const float* __restrict__ coef,
                         float* __restrict__ out, int ne4, int n_edges) {
    int t = blockIdx.x * blockDim.x + threadIdx.x;
    int stride = gridDim.x * blockDim.x;
    for (int i = t; i < ne4; i += stride) {
        int4 s = reinterpret_cast<const int4*>(src)[i];
        float4 A;
        if (ah) {
            ushort4 h = reinterpret_cast<const ushort4*>(ah)[i];
            A.x = h2f(h.x); A.y = h2f(h.y); A.z = h2f(h.z); A.w = h2f(h.w);
        } else {
            const float* e = edge_attr + 12ll * i;
            A.x = e[0]; A.y = e[3]; A.z = e[6]; A.w = e[9];
        }
        float4 w;
        w.x = coef[s.x] * A.x;
        w.y = coef[s.y] * A.y;
        w.z = coef[s.z] * A.z;
        w.w = coef[s.w] * A.w;
        reinterpret_cast<float4*>(out)[i] = w;
    }
    for (int e = 4 * ne4 + t; e < n_edges; e += stride) {
        float Ae = ah ? h2f(ah[e]) : edge_attr[3ll * e];
        out[e] = coef[src[e]] * Ae;
    }
}

extern "C" void kernel_launch(void* const* d_in, const int* in_sizes, int n_in,
                              void* d_out, int out_size, void* d_ws, size_t ws_size,
                              hipStream_t stream) {
    const float* vattr = (const float*)d_in[0];   // (nv, 2)
    const float* eattr = (const float*)d_in[1];   // (ne, 3)
    const int*   pair  = (const int*)d_in[2];     // (2, ne)
    int nv = in_sizes[0] / 2;
    int ne = in_sizes[1] / 3;
    const int* src = pair;                         // row 0
    float* out = (float*)d_out;

    int ne4 = ne / 4;
    auto capped = [](long long want, int cap) {
        return (int)(want < cap ? (want > 1 ? want : 1) : cap);
    };
    int fgrid = capped(((long long)ne4 + FBT - 1) / FBT, 8192);

    // main-path ws layout
    size_t off = 0;
    float* coef = (float*)((char*)d_ws + off); off += (size_t)nv * 4;
    off = (off + 255) & ~(size_t)255;
    u32* bin_total = (u32*)((char*)d_ws + off); off += (size_t)BINS * 4;
    u32* bin_base  = (u32*)((char*)d_ws + off); off += (size_t)(BINS + 1) * 4;
    off = (off + 255) & ~(size_t)255;
    u32* bh  = (u32*)((char*)d_ws + off); off += (size_t)NBLK * BINS * 4;
    off = (off + 255) & ~(size_t)255;
    u64* partial = (u64*)((char*)d_ws + off); off += ((size_t)BINS * SPLIT << VSHIFT) * 8;
    off = (off + 255) & ~(size_t)255;
    uint2* rec = (uint2*)((char*)d_ws + off); off += 8ull * ne;
    off = (off + 255) & ~(size_t)255;
    u16* ah = (u16*)((char*)d_ws + off); off += 2ull * ne;
    // chunk: multiple of SUB so sub-chunk bases stay 4-aligned for int4/float4
    long long chunk_ll = ((((long long)ne + NBLK - 1) / NBLK) + SUB - 1) / SUB * SUB;
    bool main_ok = ws_size >= off && nv <= (BINS << VSHIFT) &&
                   chunk_ll * NBLK < 2147000000ll;
    int chunk = (int)chunk_ll;

    if (main_ok) {
        hist_k<<<NBLK, SBT, 0, stream>>>(src, ne, chunk, bh);
        scan_col_k<<<BINS, BT, 0, stream>>>(bh, bin_total);
        scan_bins_k<<<1, BT, 0, stream>>>(bin_total, bin_base);
        scatter_k<<<NBLK, SBT, 0, stream>>>(eattr, src, bh, bin_base, rec, ah, ne, chunk);
        accum_part_k<<<BINS * SPLIT, BT, 0, stream>>>(rec, bin_base, partial);
        coef_part_k<<<capped(((long long)nv + BT - 1) / BT, 2048), BT, 0, stream>>>(partial, vattr, coef, nv);
        finalize<<<fgrid, FBT, 0, stream>>>(ah, eattr, src, coef, out, ne4, ne);
    } else {
        // fallback: packed u64 atomics
        u64* accp = (u64*)d_ws;
        float* fcoef = (float*)(accp + nv);
        size_t fb_base = (size_t)nv * 12;
        fb_base = (fb_base + 255) & ~(size_t)255;
        u16* fah = nullptr;
        if (ws_size >= fb_base + 2ull * ne)
            fah = (u16*)((char*)d_ws + fb_base);
        int zgrid = capped(((long long)nv + BT - 1) / BT, 2048);
        int agrid = capped(((long long)ne + BT - 1) / BT, 4096);
        int cgrid = capped(((long long)nv + BT - 1) / BT, 2048);
        zero_u64<<<zgrid, BT, 0, stream>>>(accp, nv);
        accum_packed<<<agrid, BT, 0, stream>>>(eattr, src, accp, fah, ne);
        coef_packed<<<cgrid, BT, 0, stream>>>(vattr, accp, fcoef, nv);
        finalize<<<fgrid, FBT, 0, stream>>>(fah, eattr, src, fcoef, out, ne4, ne);
    }
}